// Round 1
// baseline (16098.125 us; speedup 1.0000x reference)
//
#include <hip/hip_runtime.h>
#include <math.h>

#define IN_DIM 8192
#define HID 128
#define NSTEPS 4096   // reference file: STEPS = 4096 (passed as d_in[9], constant)

__device__ __forceinline__ float sigm(float x) { return 1.f / (1.f + __expf(-x)); }
__device__ __forceinline__ float tanh_f(float x) {
    x = fminf(fmaxf(x, -15.f), 15.f);          // avoid inf/inf NaN
    float e = __expf(2.f * x);
    return (e - 1.f) / (e + 1.f);
}

// ---------------------------------------------------------------------------
// Kernel 1: M = W_enc @ W_dec  (128x128), cvec = W_enc@b_dec + b_enc,
//           e1 = W_enc@x0 + b_enc.  Grid: 128 blocks (one per row p), 128 thr.
// ---------------------------------------------------------------------------
__global__ __launch_bounds__(128) void k_precompute_M(
    const float* __restrict__ W_enc, const float* __restrict__ W_dec,
    const float* __restrict__ b_enc, const float* __restrict__ b_dec,
    const float* __restrict__ x0,
    float* __restrict__ M, float* __restrict__ cvec, float* __restrict__ e1)
{
    const int p = blockIdx.x;
    const int t = threadIdx.x;              // 0..127 (= output column q)
    __shared__ float wl[128];
    __shared__ float red[256];
    float m0 = 0.f, m1 = 0.f, m2 = 0.f, m3 = 0.f, cacc = 0.f, eacc = 0.f;
    for (int i0 = 0; i0 < IN_DIM; i0 += 128) {
        float w = W_enc[(size_t)p * IN_DIM + i0 + t];   // coalesced
        cacc = fmaf(w, b_dec[i0 + t], cacc);
        eacc = fmaf(w, x0[i0 + t], eacc);
        wl[t] = w;
        __syncthreads();
#pragma unroll 8
        for (int k = 0; k < 128; k += 4) {              // W_dec reads coalesced in t
            m0 = fmaf(wl[k],     W_dec[(size_t)(i0 + k) * HID + t], m0);
            m1 = fmaf(wl[k + 1], W_dec[(size_t)(i0 + k + 1) * HID + t], m1);
            m2 = fmaf(wl[k + 2], W_dec[(size_t)(i0 + k + 2) * HID + t], m2);
            m3 = fmaf(wl[k + 3], W_dec[(size_t)(i0 + k + 3) * HID + t], m3);
        }
        __syncthreads();
    }
    M[p * HID + t] = (m0 + m1) + (m2 + m3);
    red[t] = cacc; red[128 + t] = eacc;
    __syncthreads();
    for (int s = 64; s > 0; s >>= 1) {
        if (t < s) { red[t] += red[t + s]; red[128 + t] += red[128 + t + s]; }
        __syncthreads();
    }
    if (t == 0) { cvec[p] = red[0] + b_enc[p]; e1[p] = red[128] + b_enc[p]; }
}

// ---------------------------------------------------------------------------
// Kernel 2: G rows 0..383 = W_ih@M, rows 384..767 = W_hh (copy).
//           gb[0..383] = W_ih@cvec + bias, gb[384..767] = 0.
//           ig1 = W_ih@e1 + bias.  Grid: 768 blocks, 128 threads.
// ---------------------------------------------------------------------------
__global__ __launch_bounds__(128) void k_precompute_G(
    const float* __restrict__ W_ih, const float* __restrict__ W_hh,
    const float* __restrict__ bias, const float* __restrict__ M,
    const float* __restrict__ cvec, const float* __restrict__ e1,
    float* __restrict__ G, float* __restrict__ gb, float* __restrict__ ig1)
{
    const int r = blockIdx.x;
    const int q = threadIdx.x;
    if (r >= 384) {
        G[(size_t)r * HID + q] = W_hh[(size_t)(r - 384) * HID + q];
        if (q == 0) gb[r] = 0.f;
        return;
    }
    __shared__ float red[256];
    float a0 = 0.f, a1 = 0.f, a2 = 0.f, a3 = 0.f;
#pragma unroll 8
    for (int k = 0; k < HID; k += 4) {   // W_ih[r][k] scalar-uniform, M coalesced
        a0 = fmaf(W_ih[r * HID + k],     M[(k) * HID + q], a0);
        a1 = fmaf(W_ih[r * HID + k + 1], M[(k + 1) * HID + q], a1);
        a2 = fmaf(W_ih[r * HID + k + 2], M[(k + 2) * HID + q], a2);
        a3 = fmaf(W_ih[r * HID + k + 3], M[(k + 3) * HID + q], a3);
    }
    G[(size_t)r * HID + q] = (a0 + a1) + (a2 + a3);
    float wq = W_ih[r * HID + q];
    red[q] = wq * cvec[q];
    red[128 + q] = wq * e1[q];
    __syncthreads();
    for (int s = 64; s > 0; s >>= 1) {
        if (q < s) { red[q] += red[q + s]; red[128 + q] += red[128 + q + s]; }
        __syncthreads();
    }
    if (q == 0) { gb[r] = red[0] + bias[r]; ig1[r] = red[128] + bias[r]; }
}

// ---------------------------------------------------------------------------
// Kernel 3: sequential GRU scan. ONE block, 768 threads (12 waves on 1 CU).
// Thread r owns row r of G in registers (32 float4 = 128 VGPR).
// Per step: g = G@h + gb  (768x128 matvec), then 128 threads do the gates.
// H[t] = h_{t+1}, t = 0..4095.
// ---------------------------------------------------------------------------
__global__ __launch_bounds__(768) void k_recurrence(
    const float* __restrict__ G, const float* __restrict__ gb,
    const float* __restrict__ ig1, const float* __restrict__ bias_n,
    float* __restrict__ H)
{
    const int r = threadIdx.x;              // 0..767
    __shared__ float h_lds[HID];
    __shared__ float g_lds[6 * HID];        // 768
    float4 wv[32];
    const float4* grow = (const float4*)(G + (size_t)r * HID);
#pragma unroll 32
    for (int k = 0; k < 32; ++k) wv[k] = grow[k];
    const float gbr = gb[r];
    const float bnr = (r < HID) ? bias_n[r] : 0.f;

    // step 1: h0 = 0 => hg = 0
    if (r < HID) {
        float ir = ig1[r], iz = ig1[HID + r], inn = ig1[2 * HID + r];
        float rg = sigm(ir), zg = sigm(iz);
        float ng = tanh_f(fmaf(rg, bnr, inn));
        float h1 = ng - zg * ng;            // n + z*(0 - n)
        h_lds[r] = h1;
        H[r] = h1;
    }
    __syncthreads();

    for (int t = 1; t < NSTEPS; ++t) {
        const float4* h4 = (const float4*)h_lds;
        float a0 = gbr, a1 = 0.f, a2 = 0.f, a3 = 0.f;
#pragma unroll 32
        for (int k = 0; k < 32; ++k) {      // wave-uniform LDS addr -> broadcast
            float4 hv = h4[k];
            a0 = fmaf(wv[k].x, hv.x, a0);
            a1 = fmaf(wv[k].y, hv.y, a1);
            a2 = fmaf(wv[k].z, hv.z, a2);
            a3 = fmaf(wv[k].w, hv.w, a3);
        }
        g_lds[r] = (a0 + a1) + (a2 + a3);
        __syncthreads();
        if (r < HID) {                      // waves 0,1 only; uniform branch
            float ir = g_lds[r], iz = g_lds[HID + r], inn = g_lds[2 * HID + r];
            float hr = g_lds[3 * HID + r], hz = g_lds[4 * HID + r], hn = g_lds[5 * HID + r];
            float rg = sigm(ir + hr);
            float zg = sigm(iz + hz);
            float ng = tanh_f(inn + rg * (hn + bnr));
            float hp = h_lds[r];
            float hnew = ng + zg * (hp - ng);
            h_lds[r] = hnew;
            H[(size_t)t * HID + r] = hnew;
        }
        __syncthreads();
    }
}

// ---------------------------------------------------------------------------
// Kernel 4: out[t][i] = dot(H[t][:], W_dec[i][:]) + b_dec[i]
// GEMM M=4096(t) N=8192(i) K=128, fp32 vector. 64x64 tiles, 256 threads,
// 4x4 micro-tile (strided by 16), XOR-swizzled LDS (64KB total, conflict-free).
// ---------------------------------------------------------------------------
__global__ __launch_bounds__(256) void k_decode(
    const float* __restrict__ H, const float* __restrict__ W_dec,
    const float* __restrict__ b_dec, float* __restrict__ out)
{
    __shared__ float4 As[64 * 32];   // [t][k4], k4 XOR-swizzled by (t&7)
    __shared__ float4 Bs[64 * 32];   // [i][k4]
    const int tid = threadIdx.x;
    const int t0 = blockIdx.y * 64;
    const int i0 = blockIdx.x * 64;
#pragma unroll 8
    for (int j = 0; j < 8; ++j) {
        int f = tid + 256 * j;        // 0..2047 float4s, coalesced
        int t = f >> 5;
        int k4 = f & 31;
        int sw = k4 ^ (t & 7);
        As[t * 32 + sw] = *(const float4*)(H + (size_t)(t0 + t) * HID + 4 * k4);
        Bs[t * 32 + sw] = *(const float4*)(W_dec + (size_t)(i0 + t) * HID + 4 * k4);
    }
    __syncthreads();
    const int tx = tid & 15, ty = tid >> 4;
    const int xa = ty & 7, xb = tx & 7;
    float acc[4][4] = {{0.f}};
#pragma unroll 8
    for (int k4 = 0; k4 < 32; ++k4) {
        float4 a[4], b[4];
        int ia = k4 ^ xa, ib = k4 ^ xb;
#pragma unroll
        for (int u = 0; u < 4; ++u) a[u] = As[(ty + 16 * u) * 32 + ia];
#pragma unroll
        for (int v = 0; v < 4; ++v) b[v] = Bs[(tx + 16 * v) * 32 + ib];
#pragma unroll
        for (int u = 0; u < 4; ++u)
#pragma unroll
            for (int v = 0; v < 4; ++v) {
                acc[u][v] = fmaf(a[u].x, b[v].x, acc[u][v]);
                acc[u][v] = fmaf(a[u].y, b[v].y, acc[u][v]);
                acc[u][v] = fmaf(a[u].z, b[v].z, acc[u][v]);
                acc[u][v] = fmaf(a[u].w, b[v].w, acc[u][v]);
            }
    }
#pragma unroll
    for (int u = 0; u < 4; ++u) {
        int t = t0 + ty + 16 * u;
#pragma unroll
        for (int v = 0; v < 4; ++v) {
            int i = i0 + tx + 16 * v;
            out[(size_t)t * IN_DIM + i] = acc[u][v] + b_dec[i];
        }
    }
}

// ---------------------------------------------------------------------------
extern "C" void kernel_launch(void* const* d_in, const int* in_sizes, int n_in,
                              void* d_out, int out_size, void* d_ws, size_t ws_size,
                              hipStream_t stream)
{
    const float* x0     = (const float*)d_in[0];
    const float* W_enc  = (const float*)d_in[1];
    const float* b_enc  = (const float*)d_in[2];
    const float* W_ih   = (const float*)d_in[3];
    const float* W_hh   = (const float*)d_in[4];
    const float* bias   = (const float*)d_in[5];
    const float* bias_n = (const float*)d_in[6];
    const float* W_dec  = (const float*)d_in[7];
    const float* b_dec  = (const float*)d_in[8];
    float* out = (float*)d_out;

    // workspace layout (floats): needs ~2.56 MB
    float* ws   = (float*)d_ws;
    float* M    = ws;                 // 16384
    float* cvec = ws + 16384;         // 128
    float* e1   = ws + 16512;         // 128
    float* ig1  = ws + 16640;         // 384
    float* gb   = ws + 17024;         // 768
    float* G    = ws + 17792;         // 98304   (16B-aligned)
    float* H    = ws + 116096;        // 524288  (16B-aligned)

    k_precompute_M<<<128, 128, 0, stream>>>(W_enc, W_dec, b_enc, b_dec, x0, M, cvec, e1);
    k_precompute_G<<<768, 128, 0, stream>>>(W_ih, W_hh, bias, M, cvec, e1, G, gb, ig1);
    k_recurrence<<<1, 768, 0, stream>>>(G, gb, ig1, bias_n, H);
    dim3 grid(IN_DIM / 64, NSTEPS / 64);
    k_decode<<<grid, 256, 0, stream>>>(H, W_dec, b_dec, out);
}